// Round 1
// baseline (922.426 us; speedup 1.0000x reference)
//
#include <hip/hip_runtime.h>
#include <hip/hip_bf16.h>

#define VOCAB 29
#define VEC   512
#define HID   1024
#define SEN   64
#define BATCH 2048

typedef __bf16 bf16_t;
typedef bf16_t bf16x8 __attribute__((ext_vector_type(8)));
typedef float  floatx4 __attribute__((ext_vector_type(4)));

// ---------------- prep: W_hh fp32 -> bf16 ----------------
__global__ void cvt_whh(const float* __restrict__ w, bf16_t* __restrict__ o, int n) {
    int i = blockIdx.x * blockDim.x + threadIdx.x;
    if (i < n) o[i] = (bf16_t)w[i];
}

// ---------------- prep: W_cls fp32 [65][1024] -> bf16 padded [80][1024] ----------------
__global__ void cvt_wcls(const float* __restrict__ w, bf16_t* __restrict__ o) {
    int i = blockIdx.x * blockDim.x + threadIdx.x;
    if (i >= 80 * HID) return;
    o[i] = (i < 65 * HID) ? (bf16_t)w[i] : (bf16_t)0.0f;
}

// ---------------- prep: proj[v][h] = dot(emb[v], W_ih[h]) (fp32) ----------------
__global__ void proj_kernel(const float* __restrict__ emb, const float* __restrict__ wih,
                            float* __restrict__ proj) {
    int idx = blockIdx.x * blockDim.x + threadIdx.x;
    if (idx >= VOCAB * HID) return;
    int v = idx / HID, h = idx % HID;
    const float* e = emb + v * VEC;
    const float* w = wih + h * VEC;
    float s = 0.f;
    for (int k = 0; k < VEC; k += 4) {
        float4 ev = *(const float4*)(e + k);
        float4 wv = *(const float4*)(w + k);
        s += ev.x * wv.x + ev.y * wv.y + ev.z * wv.z + ev.w * wv.w;
    }
    proj[idx] = s;
}

// exact identity tanh(x) = 1 - 2/(exp(2x)+1); fp32 rounding error << bf16 ulp
__device__ __forceinline__ float fast_tanh(float x) {
    float e = __expf(2.0f * x);
    return 1.0f - 2.0f / (e + 1.0f);
}

// async global->LDS 16B copy. LDS dest: wave-uniform base + lane*16 (HW rule).
__device__ __forceinline__ void load16_to_lds(const bf16_t* g, bf16_t* l) {
    auto gp = reinterpret_cast<const __attribute__((address_space(1))) unsigned int*>(
        reinterpret_cast<uintptr_t>(g));
    auto lp = reinterpret_cast<__attribute__((address_space(3))) unsigned int*>(
        static_cast<unsigned int>(reinterpret_cast<uintptr_t>(l)));
    __builtin_amdgcn_global_load_lds(gp, lp, 16, 0, 0);
}

// ---------------- RNN step: h_out = tanh(proj[x[:,t]] + h_in @ W_hh^T) ----------------
// v2 structure: whole W_hh slice [BN=64][HID=1024] resident in LDS (128 KB),
// staged in two K-halves via global_load_lds (XOR-swizzled 16B chunks: phys = glob ^ (row&7),
// ds_read_b128 frag reads land 2-way conflicts = free). Only TWO barriers per step
// (vs 16 barrier-drains before). A fragments read DIRECTLY global->VGPR in MFMA
// layout (no LDS staging: zero reuse within block), double-buffered 8-chunk groups
// (~400+ cyc prefetch distance covers L2-hit latency). K-loop itself is barrier-free.
// h stays XCD-local across steps: all 16 n-blocks of an m-panel have linear id ≡ bx (mod 8).
#define BM 128
#define BN 64

__global__ __launch_bounds__(256)
void rnn_step(const bf16_t* __restrict__ h_in, const bf16_t* __restrict__ whh,
              const float* __restrict__ proj, const int* __restrict__ x,
              bf16_t* __restrict__ h_out, int t, int first)
{
    __shared__ __align__(16) bf16_t Bsh[BN][HID];   // 128 KB, per-row 16B-chunk XOR swizzle
    __shared__ int tok_sh[BM];

    const int tid  = threadIdx.x;
    const int m0   = blockIdx.x * BM;
    const int n0   = blockIdx.y * BN;
    const int wave = tid >> 6;
    const int lane = tid & 63;
    const int wm   = wave * 32;        // 4 waves split m: wave tile 32 x 64
    const int q    = lane >> 4;
    const int l16  = lane & 15;
    const int l7   = l16 & 7;

    if (tid < BM) tok_sh[tid] = x[(m0 + tid) * SEN + t];

    floatx4 acc[2][4];
#pragma unroll
    for (int i = 0; i < 2; i++)
#pragma unroll
        for (int j = 0; j < 4; j++) acc[i][j] = (floatx4){0.f, 0.f, 0.f, 0.f};

    // A-fragment global base: lane (q,l16) of wave holds h_in[row][k*32 + q*8 .. +7]
    const bf16_t* hA = h_in + (m0 + wm + l16) * HID + q * 8;

    bf16x8 af[2][8][2];   // [group buf][chunk in group][mi]

#define ISSUE_AF(BUF, KBASE)                                                     \
    _Pragma("unroll")                                                            \
    for (int j = 0; j < 8; j++) {                                                \
        af[BUF][j][0] = *(const bf16x8*)(hA + ((KBASE) + j) * 32);               \
        af[BUF][j][1] = *(const bf16x8*)(hA + 16 * HID + ((KBASE) + j) * 32);    \
    }

#define COMPUTE_GROUP(BUF, KBASE)                                                \
    _Pragma("unroll")                                                            \
    for (int j = 0; j < 8; j++) {                                                \
        const int p = (4 * ((KBASE) + j) + q) ^ l7;  /* phys 16B chunk in row */ \
        bf16x8 b0 = *(const bf16x8*)&Bsh[l16][p * 8];                            \
        bf16x8 b1 = *(const bf16x8*)&Bsh[16 + l16][p * 8];                       \
        bf16x8 b2 = *(const bf16x8*)&Bsh[32 + l16][p * 8];                       \
        bf16x8 b3 = *(const bf16x8*)&Bsh[48 + l16][p * 8];                       \
        acc[0][0] = __builtin_amdgcn_mfma_f32_16x16x32_bf16(af[BUF][j][0], b0, acc[0][0], 0, 0, 0); \
        acc[0][1] = __builtin_amdgcn_mfma_f32_16x16x32_bf16(af[BUF][j][0], b1, acc[0][1], 0, 0, 0); \
        acc[0][2] = __builtin_amdgcn_mfma_f32_16x16x32_bf16(af[BUF][j][0], b2, acc[0][2], 0, 0, 0); \
        acc[0][3] = __builtin_amdgcn_mfma_f32_16x16x32_bf16(af[BUF][j][0], b3, acc[0][3], 0, 0, 0); \
        acc[1][0] = __builtin_amdgcn_mfma_f32_16x16x32_bf16(af[BUF][j][1], b0, acc[1][0], 0, 0, 0); \
        acc[1][1] = __builtin_amdgcn_mfma_f32_16x16x32_bf16(af[BUF][j][1], b1, acc[1][1], 0, 0, 0); \
        acc[1][2] = __builtin_amdgcn_mfma_f32_16x16x32_bf16(af[BUF][j][1], b2, acc[1][2], 0, 0, 0); \
        acc[1][3] = __builtin_amdgcn_mfma_f32_16x16x32_bf16(af[BUF][j][1], b3, acc[1][3], 0, 0, 0); \
    }

    if (!first) {
        // ---- stage B K-half 0 (elems 0..511): wave handles row r = it*4+wave,
        //      64 lanes = 64 chunks; dest is lane-linear (DMA rule), source XOR'd.
#pragma unroll
        for (int it = 0; it < 16; it++) {
            const int r = it * 4 + wave;
            load16_to_lds(whh + (n0 + r) * HID + (lane ^ (r & 7)) * 8,
                          &Bsh[r][lane * 8]);
        }
        // issue A group 0 (chunks 0..7) — in flight during the B-half-0 drain
        ISSUE_AF(0, 0)
    }
    __syncthreads();   // drains B half 0 (+af grp0); covers tok_sh on all paths

    if (!first) {
        // ---- stage B K-half 1 (elems 512..1023): hidden under chunks 0..15 compute
#pragma unroll
        for (int it = 0; it < 16; it++) {
            const int r = it * 4 + wave;
            load16_to_lds(whh + (n0 + r) * HID + 512 + (lane ^ (r & 7)) * 8,
                          &Bsh[r][512 + lane * 8]);
        }
        ISSUE_AF(1, 8)           // chunks 8..15
        COMPUTE_GROUP(0, 0)      // chunks 0..7   (B half 0)
        ISSUE_AF(0, 16)          // chunks 16..23
        COMPUTE_GROUP(1, 8)      // chunks 8..15  (B half 0)
        __syncthreads();         // B half 1 now visible to all waves
        ISSUE_AF(1, 24)          // chunks 24..31
        COMPUTE_GROUP(0, 16)     // chunks 16..23 (B half 1)
        COMPUTE_GROUP(1, 24)     // chunks 24..31 (B half 1)
    }

#undef ISSUE_AF
#undef COMPUTE_GROUP

    // epilogue: C/D row = q*4+reg, col = l16 (HW-verified); + proj + tanh
#pragma unroll
    for (int mi = 0; mi < 2; mi++) {
#pragma unroll
        for (int r = 0; r < 4; r++) {
            int lm = wm + mi * 16 + q * 4 + r;
            int gm = m0 + lm;
            const float* pr = proj + tok_sh[lm] * HID;
#pragma unroll
            for (int ni = 0; ni < 4; ni++) {
                int gn = n0 + ni * 16 + l16;
                float v = acc[mi][ni][r] + pr[gn];
                h_out[gm * HID + gn] = (bf16_t)fast_tanh(v);
            }
        }
    }
}

// ---------------- classifier: out = h @ W_cls^T + b_cls via MFMA (proven R2) ----------------
#define CBM 128
#define CLDK 72
__global__ __launch_bounds__(256)
void classifier_mfma(const bf16_t* __restrict__ h, const bf16_t* __restrict__ wcls,
                     const float* __restrict__ bcls, float* __restrict__ out)
{
    __shared__ __align__(16) bf16_t Ash[CBM][CLDK];
    __shared__ __align__(16) bf16_t Bsh[80][CLDK];

    const int tid = threadIdx.x;
    const int m0 = blockIdx.x * CBM;
    const int wave = tid >> 6, lane = tid & 63;
    const int wm = wave * 32;
    const int q = lane >> 4, l16 = lane & 15;

    floatx4 acc[2][5];
#pragma unroll
    for (int i = 0; i < 2; i++)
#pragma unroll
        for (int j = 0; j < 5; j++) acc[i][j] = (floatx4){0.f, 0.f, 0.f, 0.f};

    for (int kk = 0; kk < HID; kk += 64) {
#pragma unroll
        for (int it = 0; it < 4; it++) {
            int idx = tid + it * 256, r = idx >> 3, c = (idx & 7) * 8;
            *(uint4*)&Ash[r][c] = *(const uint4*)&h[(m0 + r) * HID + kk + c];
        }
#pragma unroll
        for (int it = 0; it < 3; it++) {
            int idx = tid + it * 256;
            if (idx < 640) {
                int r = idx >> 3, c = (idx & 7) * 8;
                *(uint4*)&Bsh[r][c] = *(const uint4*)&wcls[r * HID + kk + c];
            }
        }
        __syncthreads();
#pragma unroll
        for (int ks = 0; ks < 64; ks += 32) {
            bf16x8 af[2], bfr[5];
#pragma unroll
            for (int mi = 0; mi < 2; mi++)
                af[mi] = *(const bf16x8*)&Ash[wm + mi * 16 + l16][ks + q * 8];
#pragma unroll
            for (int ni = 0; ni < 5; ni++)
                bfr[ni] = *(const bf16x8*)&Bsh[ni * 16 + l16][ks + q * 8];
#pragma unroll
            for (int mi = 0; mi < 2; mi++)
#pragma unroll
                for (int ni = 0; ni < 5; ni++)
                    acc[mi][ni] = __builtin_amdgcn_mfma_f32_16x16x32_bf16(
                        af[mi], bfr[ni], acc[mi][ni], 0, 0, 0);
        }
        __syncthreads();
    }

#pragma unroll
    for (int mi = 0; mi < 2; mi++) {
#pragma unroll
        for (int r = 0; r < 4; r++) {
            int gm = m0 + wm + mi * 16 + q * 4 + r;
#pragma unroll
            for (int ni = 0; ni < 5; ni++) {
                int gn = ni * 16 + l16;
                if (gn < SEN + 1)
                    out[gm * (SEN + 1) + gn] = acc[mi][ni][r] + bcls[gn];
            }
        }
    }
}

extern "C" void kernel_launch(void* const* d_in, const int* in_sizes, int n_in,
                              void* d_out, int out_size, void* d_ws, size_t ws_size,
                              hipStream_t stream)
{
    const int*   x     = (const int*)  d_in[0];
    const float* emb   = (const float*)d_in[1];
    const float* w_ih  = (const float*)d_in[2];
    const float* w_hh  = (const float*)d_in[3];
    const float* w_cls = (const float*)d_in[4];
    const float* b_cls = (const float*)d_in[5];
    float* out = (float*)d_out;

    char* ws = (char*)d_ws;
    bf16_t* whh_bf  = (bf16_t*)ws;                                  // 2 MB
    float*  proj    = (float*)(ws + (2u << 20));                    // 128 KB
    bf16_t* wcls_bf = (bf16_t*)(ws + (2u << 20) + (128u << 10));    // 160 KB
    bf16_t* h0      = (bf16_t*)(ws + (2u << 20) + (288u << 10));    // 4 MB
    bf16_t* h1      = (bf16_t*)(ws + (6u << 20) + (288u << 10));    // 4 MB

    cvt_whh<<<(HID * HID) / 256, 256, 0, stream>>>(w_hh, whh_bf, HID * HID);
    proj_kernel<<<(VOCAB * HID + 255) / 256, 256, 0, stream>>>(emb, w_ih, proj);
    cvt_wcls<<<(80 * HID) / 256, 256, 0, stream>>>(w_cls, wcls_bf);

    dim3 grid(BATCH / BM, HID / BN);   // (16,16) = 256 blocks, 1/CU
    bf16_t* bufs[2] = {h0, h1};
    for (int t = 0; t < SEN; t++) {
        bf16_t* hi = bufs[(t + 1) & 1];   // ignored when t==0 (first=1)
        bf16_t* ho = bufs[t & 1];
        rnn_step<<<grid, 256, 0, stream>>>(hi, whh_bf, proj, x, ho, t, t == 0 ? 1 : 0);
    }
    classifier_mfma<<<BATCH / CBM, 256, 0, stream>>>(bufs[1], wcls_bf, b_cls, out);
}